// Round 1
// baseline (70.747 us; speedup 1.0000x reference)
//
#include <hip/hip_runtime.h>

// ConvLogicTreeLayer: B=16, C_in=64, H=W=32, C_out=128, K=3, PAD=1, TREE_DEPTH=3
// Refold: each softmax-weighted mixture of the 16 logic ops is affine in
// {1, a, b, ab}. Precompute 4 coeffs per (o, gate), gates 0..3 only.

#define C_OUT 128
#define C_IN  64
#define HW    32
#define NGATE 4

__device__ __forceinline__ float gate_eval(float4 c, float a, float b) {
    // c0 + ca*a + cb*b + cab*a*b
    return fmaf(a * b, c.w, fmaf(a, c.y, fmaf(b, c.z, c.x)));
}

// One thread per (o, gate): softmax over 16, fold into 4 coeffs.
__global__ void prep_coeffs(const float* __restrict__ w, float* __restrict__ coef) {
    int t = blockIdx.x * blockDim.x + threadIdx.x;
    if (t >= C_OUT * NGATE) return;
    int o = t >> 2, g = t & 3;
    const float* wp = w + (o * 7 + g) * 16;
    float v[16];
    float m = -1e30f;
    #pragma unroll
    for (int i = 0; i < 16; ++i) { v[i] = wp[i]; m = fmaxf(m, v[i]); }
    float s = 0.f;
    #pragma unroll
    for (int i = 0; i < 16; ++i) { v[i] = expf(v[i] - m); s += v[i]; }
    float inv = 1.f / s;
    #pragma unroll
    for (int i = 0; i < 16; ++i) v[i] *= inv;
    // op table coefficients in {1, a, b, ab}:
    // 0:0 | 1:ab | 2:a-ab | 3:a | 4:b-ab | 5:b | 6:a+b-2ab | 7:a+b-ab
    // 8:1-(a+b-ab) | 9:1-(a+b-2ab) | 10:1-b | 11:1-b+ab | 12:1-a | 13:1-a+ab
    // 14:1-ab | 15:1
    float c0  = v[8] + v[9] + v[10] + v[11] + v[12] + v[13] + v[14] + v[15];
    float ca  = v[2] + v[3] + v[6] + v[7] - v[8] - v[9] - v[12] - v[13];
    float cb  = v[4] + v[5] + v[6] + v[7] - v[8] - v[9] - v[10] - v[11];
    float cab = v[1] - v[2] - v[4] - 2.f * v[6] - v[7] + v[8] + 2.f * v[9]
              + v[11] + v[13] - v[14];
    ((float4*)coef)[t] = make_float4(c0, ca, cb, cab);
}

// One block per (b, o); one thread per pixel.
__global__ __launch_bounds__(1024) void logic_tree(
    const float* __restrict__ x, const int* __restrict__ leaf_idx,
    const float* __restrict__ coef, float* __restrict__ out)
{
    int blk = blockIdx.x;         // 0..2047
    int b = blk >> 7;             // /128
    int o = blk & (C_OUT - 1);
    int pix = threadIdx.x;        // 0..1023
    int h = pix >> 5, w = pix & (HW - 1);

    // Block-uniform leaf decode (channel, dy, dx per leaf slot).
    int cch[8], dy[8], dx[8];
    #pragma unroll
    for (int j = 0; j < 8; ++j) {
        int li = leaf_idx[o * 8 + j];      // uniform per block
        int c = li / 9;
        int kk = li - c * 9;
        int ky = kk / 3;
        cch[j] = c;
        dy[j] = ky - 1;
        dx[j] = (kk - ky * 3) - 1;
    }
    float4 cf0 = ((const float4*)coef)[o * 4 + 0];
    float4 cf1 = ((const float4*)coef)[o * 4 + 1];
    float4 cf2 = ((const float4*)coef)[o * 4 + 2];
    float4 cf3 = ((const float4*)coef)[o * 4 + 3];

    const float* xb = x + (size_t)b * C_IN * HW * HW;
    float v[8];
    #pragma unroll
    for (int j = 0; j < 8; ++j) {
        int hh = h + dy[j], ww = w + dx[j];
        bool ok = ((unsigned)hh < HW) & ((unsigned)ww < HW);
        v[j] = ok ? xb[(cch[j] * HW + hh) * HW + ww] : 0.f;
    }

    // level 0: pairs (0,1)(2,3)(4,5)(6,7) with gates 0,1,2,3
    float p0 = gate_eval(cf0, v[0], v[1]);
    float p1 = gate_eval(cf1, v[2], v[3]);
    float p2 = gate_eval(cf2, v[4], v[5]);
    float p3 = gate_eval(cf3, v[6], v[7]);
    // level 1: pairs (p0,p1)(p2,p3) with gates 1,2
    float q0 = gate_eval(cf1, p0, p1);
    float q1 = gate_eval(cf2, p2, p3);
    // level 2: pair (q0,q1) with gate 3
    float r = gate_eval(cf3, q0, q1);

    out[((size_t)b * C_OUT + o) * (HW * HW) + pix] = r;
}

extern "C" void kernel_launch(void* const* d_in, const int* in_sizes, int n_in,
                              void* d_out, int out_size, void* d_ws, size_t ws_size,
                              hipStream_t stream) {
    const float* x       = (const float*)d_in[0];
    const float* weights = (const float*)d_in[1];
    const int*   leaves  = (const int*)d_in[2];
    float* out  = (float*)d_out;
    float* coef = (float*)d_ws;   // 128*4*4 floats = 8 KB

    prep_coeffs<<<2, 256, 0, stream>>>(weights, coef);
    logic_tree<<<16 * C_OUT, 1024, 0, stream>>>(x, leaves, coef, out);
}

// Round 2
// 68.709 us; speedup vs baseline: 1.0297x; 1.0297x over previous
//
#include <hip/hip_runtime.h>

// ConvLogicTreeLayer: B=16, C_in=64, H=W=32, C_out=128, K=3, PAD=1, TREE_DEPTH=3
// Refold: softmax-weighted mixture of the 16 logic ops is affine in
// {1, a, b, ab} -> 4 coeffs per (o, gate); only gates 0..3 are ever used
// (level0: gates 0-3, level1: gates 1-2, level2: gate 3).
// This version: single fused kernel, 4 pixels per thread (float4 along W).

#define C_OUT 128
#define C_IN  64
#define HW    32

__device__ __forceinline__ float4 ld4u(const float* p) {
    float4 v;
    __builtin_memcpy(&v, p, sizeof(float4));   // 4B-aligned ok
    return v;
}

__device__ __forceinline__ float4 gate4(const float4 c, const float4 a, const float4 b) {
    float4 r;
    r.x = fmaf(a.x * b.x, c.w, fmaf(a.x, c.y, fmaf(b.x, c.z, c.x)));
    r.y = fmaf(a.y * b.y, c.w, fmaf(a.y, c.y, fmaf(b.y, c.z, c.x)));
    r.z = fmaf(a.z * b.z, c.w, fmaf(a.z, c.y, fmaf(b.z, c.z, c.x)));
    r.w = fmaf(a.w * b.w, c.w, fmaf(a.w, c.y, fmaf(b.w, c.z, c.x)));
    return r;
}

// One block per (b, o) image; 256 threads, each owns a 1x4 pixel quad.
__global__ __launch_bounds__(256) void logic_tree_fused(
    const float* __restrict__ x, const float* __restrict__ wts,
    const int* __restrict__ leaf_idx, float* __restrict__ out)
{
    const int blk = blockIdx.x;       // 0..2047
    const int b = blk >> 7;
    const int o = blk & (C_OUT - 1);

    // ---- per-block coefficient fold (threads 0..3) ----
    __shared__ float4 cf_s[4];
    if (threadIdx.x < 4) {
        const int g = threadIdx.x;
        const float* wp = wts + (o * 7 + g) * 16;
        float v[16];
        float m = -1e30f;
        #pragma unroll
        for (int i = 0; i < 16; ++i) { v[i] = wp[i]; m = fmaxf(m, v[i]); }
        float s = 0.f;
        #pragma unroll
        for (int i = 0; i < 16; ++i) { v[i] = expf(v[i] - m); s += v[i]; }
        float inv = 1.f / s;
        #pragma unroll
        for (int i = 0; i < 16; ++i) v[i] *= inv;
        // ops in {1,a,b,ab}: 0:0 1:ab 2:a-ab 3:a 4:b-ab 5:b 6:a+b-2ab 7:a+b-ab
        // 8:1-(a+b-ab) 9:1-(a+b-2ab) 10:1-b 11:1-b+ab 12:1-a 13:1-a+ab 14:1-ab 15:1
        float c0  = v[8]+v[9]+v[10]+v[11]+v[12]+v[13]+v[14]+v[15];
        float ca  = v[2]+v[3]+v[6]+v[7]-v[8]-v[9]-v[12]-v[13];
        float cb  = v[4]+v[5]+v[6]+v[7]-v[8]-v[9]-v[10]-v[11];
        float cab = v[1]-v[2]-v[4]-2.f*v[6]-v[7]+v[8]+2.f*v[9]+v[11]+v[13]-v[14];
        cf_s[g] = make_float4(c0, ca, cb, cab);
    }

    // ---- block-uniform leaf decode ----
    int cch[8], dy[8], dxx[8];
    #pragma unroll
    for (int j = 0; j < 8; ++j) {
        int li = leaf_idx[o * 8 + j];
        int c = li / 9;
        int kk = li - c * 9;
        int ky = kk / 3;
        cch[j] = c; dy[j] = ky - 1; dxx[j] = (kk - ky * 3) - 1;
    }
    __syncthreads();

    const int q = threadIdx.x & 7;     // w-quad: covers w = 4q..4q+3
    const int h = threadIdx.x >> 3;    // row
    const float* xb = x + (size_t)b * C_IN * HW * HW;

    float4 v[8];
    #pragma unroll
    for (int j = 0; j < 8; ++j) {
        int hh = h + dy[j];
        bool hok = ((unsigned)hh < HW);
        const float* rp = xb + (cch[j] * HW + (hok ? hh : 0)) * HW;
        float4 t;
        if (dxx[j] == 0) {                       // block-uniform branch
            t = ld4u(rp + 4 * q);
        } else {
            int base = 4 * q + dxx[j];           // -1..29
            int cb = min(max(base, 0), HW - 4);  // in-bounds unaligned load
            float4 u = ld4u(rp + cb);
            if (base < 0)            t = make_float4(0.f, u.x, u.y, u.z);
            else if (base > HW - 4)  t = make_float4(u.y, u.z, u.w, 0.f);
            else                     t = u;
        }
        if (!hok) t = make_float4(0.f, 0.f, 0.f, 0.f);
        v[j] = t;
    }

    const float4 cf0 = cf_s[0], cf1 = cf_s[1], cf2 = cf_s[2], cf3 = cf_s[3];
    // level 0
    float4 p0 = gate4(cf0, v[0], v[1]);
    float4 p1 = gate4(cf1, v[2], v[3]);
    float4 p2 = gate4(cf2, v[4], v[5]);
    float4 p3 = gate4(cf3, v[6], v[7]);
    // level 1
    float4 q0 = gate4(cf1, p0, p1);
    float4 q1 = gate4(cf2, p2, p3);
    // level 2
    float4 r  = gate4(cf3, q0, q1);

    float4* op = (float4*)(out + (size_t)(b * C_OUT + o) * (HW * HW));
    op[threadIdx.x] = r;   // pixel offset = 4*threadIdx.x
}

extern "C" void kernel_launch(void* const* d_in, const int* in_sizes, int n_in,
                              void* d_out, int out_size, void* d_ws, size_t ws_size,
                              hipStream_t stream) {
    const float* x       = (const float*)d_in[0];
    const float* weights = (const float*)d_in[1];
    const int*   leaves  = (const int*)d_in[2];
    float* out = (float*)d_out;
    logic_tree_fused<<<16 * C_OUT, 256, 0, stream>>>(x, weights, leaves, out);
}

// Round 3
// 65.044 us; speedup vs baseline: 1.0877x; 1.0564x over previous
//
#include <hip/hip_runtime.h>

// ConvLogicTreeLayer: B=16, C_in=64, H=W=32, C_out=128, K=3, PAD=1, TREE_DEPTH=3
// Refold: softmax mixture of the 16 logic ops is affine in {1,a,b,ab} ->
// 4 coeffs per (o,gate); only gates 0..3 used (L0: 0-3, L1: 1-2, L2: 3).
// This version: 8 px/thread, all-aligned 16B loads, +-1 column via shuffles.

#define C_OUT 128
#define C_IN  64
#define HW    32

__device__ __forceinline__ void gate8(const float4 c, const float* a,
                                      const float* b, float* r) {
    #pragma unroll
    for (int i = 0; i < 8; ++i)
        r[i] = fmaf(a[i] * b[i], c.w, fmaf(a[i], c.y, fmaf(b[i], c.z, c.x)));
}

// Load 8 horizontally-consecutive pixels of plane c, row h+dy, cols 8q+dx..+7.
// Aligned vec4 loads; dx=+-1 tap comes from neighbor lane via shuffle.
__device__ __forceinline__ void load_leaf(const float* __restrict__ xb,
                                          int c, int dy, int dx,
                                          int h, int q, float* t) {
    int hh = h + dy;
    bool hok = ((unsigned)hh < HW);
    const float* rp = xb + (c * HW + (hok ? hh : 0)) * HW + 8 * q;
    float4 e0 = *(const float4*)rp;        // 32B-aligned
    float4 e1 = *(const float4*)(rp + 4);
    float prev = __shfl_up(e1.w, 1);       // lane-1's col 8q-1
    float next = __shfl_down(e0.x, 1);     // lane+1's col 8q+8
    float e[8] = {e0.x, e0.y, e0.z, e0.w, e1.x, e1.y, e1.z, e1.w};
    float s[8];
    if (dx == 0) {                          // wave-uniform branches
        #pragma unroll
        for (int i = 0; i < 8; ++i) s[i] = e[i];
    } else if (dx < 0) {
        s[0] = (q > 0) ? prev : 0.f;
        #pragma unroll
        for (int i = 1; i < 8; ++i) s[i] = e[i - 1];
    } else {
        #pragma unroll
        for (int i = 0; i < 7; ++i) s[i] = e[i + 1];
        s[7] = (q < 3) ? next : 0.f;
    }
    #pragma unroll
    for (int i = 0; i < 8; ++i) t[i] = hok ? s[i] : 0.f;
}

// One block per (b,o) image; 128 threads, each owns a 1x8 pixel strip.
__global__ __launch_bounds__(128) void logic_tree_fused(
    const float* __restrict__ x, const float* __restrict__ wts,
    const int* __restrict__ leaf_idx, float* __restrict__ out)
{
    const int blk = blockIdx.x;       // 0..2047 == b*128 + o
    const int b = blk >> 7;
    const int o = blk & (C_OUT - 1);

    __shared__ float4 cf_s[4];
    if (threadIdx.x < 4) {
        const int g = threadIdx.x;
        const float* wp = wts + (o * 7 + g) * 16;
        float v[16];
        float m = -1e30f;
        #pragma unroll
        for (int i = 0; i < 16; ++i) { v[i] = wp[i]; m = fmaxf(m, v[i]); }
        float s = 0.f;
        #pragma unroll
        for (int i = 0; i < 16; ++i) { v[i] = expf(v[i] - m); s += v[i]; }
        float inv = 1.f / s;
        #pragma unroll
        for (int i = 0; i < 16; ++i) v[i] *= inv;
        // ops in {1,a,b,ab}: 0:0 1:ab 2:a-ab 3:a 4:b-ab 5:b 6:a+b-2ab 7:a+b-ab
        // 8:1-(a+b-ab) 9:1-(a+b-2ab) 10:1-b 11:1-b+ab 12:1-a 13:1-a+ab 14:1-ab 15:1
        float c0  = v[8]+v[9]+v[10]+v[11]+v[12]+v[13]+v[14]+v[15];
        float ca  = v[2]+v[3]+v[6]+v[7]-v[8]-v[9]-v[12]-v[13];
        float cb  = v[4]+v[5]+v[6]+v[7]-v[8]-v[9]-v[10]-v[11];
        float cab = v[1]-v[2]-v[4]-2.f*v[6]-v[7]+v[8]+2.f*v[9]+v[11]+v[13]-v[14];
        cf_s[g] = make_float4(c0, ca, cb, cab);
    }

    int cch[8], dy[8], dxx[8];
    #pragma unroll
    for (int j = 0; j < 8; ++j) {
        int li = leaf_idx[o * 8 + j];      // block-uniform
        int c = li / 9;
        int kk = li - c * 9;
        int ky = kk / 3;
        cch[j] = c; dy[j] = ky - 1; dxx[j] = (kk - ky * 3) - 1;
    }
    __syncthreads();

    const int q = threadIdx.x & 3;     // w = 8q..8q+7
    const int h = threadIdx.x >> 2;    // row 0..31
    const float* xb = x + (size_t)b * C_IN * HW * HW;

    const float4 cf0 = cf_s[0], cf1 = cf_s[1], cf2 = cf_s[2], cf3 = cf_s[3];
    float la[8], lb[8], p0[8], p1[8], q0[8], q1[8], r[8];

    load_leaf(xb, cch[0], dy[0], dxx[0], h, q, la);
    load_leaf(xb, cch[1], dy[1], dxx[1], h, q, lb);
    gate8(cf0, la, lb, p0);
    load_leaf(xb, cch[2], dy[2], dxx[2], h, q, la);
    load_leaf(xb, cch[3], dy[3], dxx[3], h, q, lb);
    gate8(cf1, la, lb, p1);
    gate8(cf1, p0, p1, q0);
    load_leaf(xb, cch[4], dy[4], dxx[4], h, q, la);
    load_leaf(xb, cch[5], dy[5], dxx[5], h, q, lb);
    gate8(cf2, la, lb, p0);
    load_leaf(xb, cch[6], dy[6], dxx[6], h, q, la);
    load_leaf(xb, cch[7], dy[7], dxx[7], h, q, lb);
    gate8(cf3, la, lb, p1);
    gate8(cf2, p0, p1, q1);
    gate8(cf3, q0, q1, r);

    float4* op = (float4*)(out + (size_t)blk * (HW * HW) + h * HW + 8 * q);
    op[0] = make_float4(r[0], r[1], r[2], r[3]);
    op[1] = make_float4(r[4], r[5], r[6], r[7]);
}

extern "C" void kernel_launch(void* const* d_in, const int* in_sizes, int n_in,
                              void* d_out, int out_size, void* d_ws, size_t ws_size,
                              hipStream_t stream) {
    const float* x       = (const float*)d_in[0];
    const float* weights = (const float*)d_in[1];
    const int*   leaves  = (const int*)d_in[2];
    float* out = (float*)d_out;
    logic_tree_fused<<<16 * C_OUT, 128, 0, stream>>>(x, weights, leaves, out);
}